// Round 1
// baseline (1099.878 us; speedup 1.0000x reference)
//
#include <hip/hip_runtime.h>

#define NVOX 400000
#define KVOL 27
#define GROUPS 4
#define CPG 16          // channels per group (in and out)
#define CTOT 64         // total channels

// Transpose weight [g][k][ci][co] -> wT [g][k][co][ci] so each output lane
// reads its 16 ci-weights contiguously (4x float4).
__global__ void transpose_w_kernel(const float* __restrict__ w, float* __restrict__ wT) {
    int t = blockIdx.x * blockDim.x + threadIdx.x;
    const int total = GROUPS * KVOL * CPG * CPG;   // 27648
    if (t >= total) return;
    int ci = t & 15;
    int co = (t >> 4) & 15;
    int gk = t >> 8;                 // g*27 + k, 0..107
    // write coalesced: wT[t] = wT[gk][co][ci]
    wT[t] = w[gk * 256 + ci * 16 + co];
}

__global__ __launch_bounds__(256) void conv_kernel(
        const float* __restrict__ feat,
        const float* __restrict__ wT,
        const float* __restrict__ bias,
        const int* __restrict__ nb,
        float* __restrict__ out) {
    int wave = (int)((blockIdx.x * blockDim.x + threadIdx.x) >> 6);  // voxel id
    int lane = threadIdx.x & 63;
    if (wave >= NVOX) return;
    int g = lane >> 4;        // group
    int c = lane & 15;        // output channel within group

    float acc = bias[lane];

    // wT as float4: offset (g*27 + k)*64 + c*4 + {0..3}
    const float4* wbase = (const float4*)wT + (size_t)g * (KVOL * 64) + c * 4;
    const int* nbv = nb + (size_t)wave * KVOL;
    const float* fg = feat + (size_t)g * CPG;   // + idx*64 later

#pragma unroll 1
    for (int k = 0; k < KVOL; ++k) {
        int idx = nbv[k];          // wave-uniform (same address across lanes)
        if (idx < 0) continue;     // wave-uniform branch
        const float4* f = (const float4*)(fg + (size_t)idx * CTOT);
        const float4* wv = wbase + k * 64;
        float4 f0 = f[0], f1 = f[1], f2 = f[2], f3 = f[3];
        float4 w0 = wv[0], w1 = wv[1], w2 = wv[2], w3 = wv[3];
        acc += f0.x * w0.x + f0.y * w0.y + f0.z * w0.z + f0.w * w0.w
             + f1.x * w1.x + f1.y * w1.y + f1.z * w1.z + f1.w * w1.w
             + f2.x * w2.x + f2.y * w2.y + f2.z * w2.z + f2.w * w2.w
             + f3.x * w3.x + f3.y * w3.y + f3.z * w3.z + f3.w * w3.w;
    }

    out[(size_t)wave * CTOT + lane] = acc;
}

extern "C" void kernel_launch(void* const* d_in, const int* in_sizes, int n_in,
                              void* d_out, int out_size, void* d_ws, size_t ws_size,
                              hipStream_t stream) {
    const float* features = (const float*)d_in[0];
    const float* weight   = (const float*)d_in[1];
    const float* bias     = (const float*)d_in[2];
    const int*   nb       = (const int*)d_in[3];
    float* out = (float*)d_out;
    float* wT  = (float*)d_ws;   // 27648 floats = 110,592 B

    const int wtotal = GROUPS * KVOL * CPG * CPG;
    transpose_w_kernel<<<(wtotal + 255) / 256, 256, 0, stream>>>(weight, wT);

    // one wave (64 lanes) per voxel, 4 voxels per 256-thread block
    int nblocks = (NVOX + 3) / 4;
    conv_kernel<<<nblocks, 256, 0, stream>>>(features, wT, bias, nb, out);
}

// Round 2
// 645.707 us; speedup vs baseline: 1.7034x; 1.7034x over previous
//
#include <hip/hip_runtime.h>
#include <hip/hip_fp16.h>

#define NVOX 400000
#define KVOL 27
#define CTOT 64
#define NTILES (NVOX / 16)          // 25000 exact
#define WTOT (4 * KVOL * 16 * 16)   // 27648 weight elements

// ---------------- ws layout ----------------
// featH : __half[NVOX*64]            offset 0          (51,200,000 B)
// nbT   : int[27*NVOX]               offset 51,200,000 (43,200,000 B)
// wsrc  : __half[27648]              offset 94,400,000 (55,296 B)
#define FEATH_OFF 0
#define NBT_OFF   51200000
#define WSRC_OFF  94400000

// feat fp32 -> fp16, 8 elements per thread
__global__ void cvt_feat_kernel(const float* __restrict__ f, __half* __restrict__ fh) {
    int t = blockIdx.x * blockDim.x + threadIdx.x;
    const int total = NVOX * CTOT / 8;   // 3,200,000
    if (t >= total) return;
    const float4* fp = (const float4*)f + (size_t)t * 2;
    float4 a = fp[0], b = fp[1];
    union { __half h[8]; uint4 u; } r;
    r.h[0] = __float2half(a.x); r.h[1] = __float2half(a.y);
    r.h[2] = __float2half(a.z); r.h[3] = __float2half(a.w);
    r.h[4] = __float2half(b.x); r.h[5] = __float2half(b.y);
    r.h[6] = __float2half(b.z); r.h[7] = __float2half(b.w);
    ((uint4*)fh)[t] = r.u;
}

// nb[v][k] -> nbT[k][v], LDS-tiled so both sides are coalesced
__global__ void transpose_nb_kernel(const int* __restrict__ nb, int* __restrict__ nbT) {
    __shared__ int s[64 * KVOL];
    int base = blockIdx.x * 64;          // voxel base, 6250 blocks
    const int* src = nb + (size_t)base * KVOL;
    for (int j = threadIdx.x; j < 64 * KVOL; j += 256) s[j] = src[j];
    __syncthreads();
    for (int j = threadIdx.x; j < 64 * KVOL; j += 256) {
        int k = j >> 6;                  // j = k*64 + v -> consecutive threads write consecutive v
        int v = j & 63;
        nbT[(size_t)k * NVOX + base + v] = s[v * KVOL + k];
    }
}

// weight[g][k][ci][co] fp32 -> wsrc f16 laid out as 16B chunks [B=g*27+k][h=ci/8][c=co][i=ci%8]
__global__ void cvt_w_kernel(const float* __restrict__ w, __half* __restrict__ ws) {
    int t = blockIdx.x * blockDim.x + threadIdx.x;
    if (t >= WTOT) return;
    int i = t & 7;
    int c = (t >> 3) & 15;
    int h = (t >> 7) & 1;
    int B = t >> 8;                      // g*27 + k
    ws[t] = __float2half(w[B * 256 + (h * 8 + i) * 16 + c]);
}

__global__ __launch_bounds__(512, 4) void conv_main_kernel(
        const __half* __restrict__ fh,
        const __half* __restrict__ wsrc,
        const float*  __restrict__ bias,
        const int*    __restrict__ nbT,
        float* __restrict__ out) {
    // f16 weights, bank-even layout: chunk index [B][h][c], B=g*27+k in [0,108)
    __shared__ uint4 wlds[108 * 32];     // 55,296 B
    const uint4* src = (const uint4*)wsrc;
    for (int j = threadIdx.x; j < 108 * 32; j += blockDim.x) wlds[j] = src[j];
    __syncthreads();

    const int lane = threadIdx.x & 63;
    const int c = lane & 15;             // output channel within group
    const int g = lane >> 4;             // group
    const int wid = blockIdx.x * (blockDim.x >> 6) + (threadIdx.x >> 6);
    const int nwaves = gridDim.x * (blockDim.x >> 6);
    const float breg = bias[lane];

    for (int tile = wid; tile < NTILES; tile += nwaves) {
        float acc[16];
#pragma unroll
        for (int v = 0; v < 16; ++v) acc[v] = 0.f;

        for (int k = 0; k < KVOL; ++k) {
            // lane v (v = lane&15) holds neighbor idx of voxel tile*16+v
            int idxv = nbT[k * NVOX + tile * 16 + c];
            unsigned long long act = __ballot(idxv >= 0);
            if (!(act & 0xFFFFull)) continue;

            const int B = g * KVOL + k;
            uint4 wa = wlds[B * 32 + c];         // w[g][k][ci=0..7][c]
            uint4 wb = wlds[B * 32 + 16 + c];    // w[g][k][ci=8..15][c]
            const __half* wh0 = (const __half*)&wa;
            const __half* wh1 = (const __half*)&wb;

#pragma unroll
            for (int v = 0; v < 16; ++v) {
                if (act & (1ull << v)) {
                    int idx = __builtin_amdgcn_readlane(idxv, v);  // uniform -> SGPR
                    const uint4* fq = (const uint4*)(fh + ((size_t)idx * CTOT + g * 16));
                    uint4 f0 = fq[0], f1 = fq[1];
                    const __half* fh0 = (const __half*)&f0;
                    const __half* fh1 = (const __half*)&f1;
                    float s = acc[v];
#pragma unroll
                    for (int i = 0; i < 8; ++i)
                        s += __half2float(fh0[i]) * __half2float(wh0[i]);
#pragma unroll
                    for (int i = 0; i < 8; ++i)
                        s += __half2float(fh1[i]) * __half2float(wh1[i]);
                    acc[v] = s;
                }
            }
        }

        int ob = tile * 16 * CTOT + lane;   // + v*64; 64 lanes contiguous 256 B per v
#pragma unroll
        for (int v = 0; v < 16; ++v) out[ob + v * CTOT] = acc[v] + breg;
    }
}

extern "C" void kernel_launch(void* const* d_in, const int* in_sizes, int n_in,
                              void* d_out, int out_size, void* d_ws, size_t ws_size,
                              hipStream_t stream) {
    const float* features = (const float*)d_in[0];
    const float* weight   = (const float*)d_in[1];
    const float* bias     = (const float*)d_in[2];
    const int*   nb       = (const int*)d_in[3];
    float* out = (float*)d_out;

    char* ws = (char*)d_ws;
    __half* featH = (__half*)(ws + FEATH_OFF);
    int*    nbT   = (int*)(ws + NBT_OFF);
    __half* wsrc  = (__half*)(ws + WSRC_OFF);

    cvt_feat_kernel<<<(NVOX * CTOT / 8 + 255) / 256, 256, 0, stream>>>(features, featH);
    transpose_nb_kernel<<<NVOX / 64, 256, 0, stream>>>(nb, nbT);
    cvt_w_kernel<<<(WTOT + 255) / 256, 256, 0, stream>>>(weight, wsrc);

    // 1024 blocks x 512 threads = 8192 waves; 2 blocks/CU (55KB LDS each) = 16 waves/CU
    conv_main_kernel<<<1024, 512, 0, stream>>>(featH, wsrc, bias, nbT, out);
}

// Round 3
// 327.217 us; speedup vs baseline: 3.3613x; 1.9733x over previous
//
#include <hip/hip_runtime.h>
#include <hip/hip_fp16.h>

#define NVOX 400000
#define KVOL 27
#define CTOT 64
#define NTILES (NVOX / 16)     // 25000 exact
#define NPAIR 14               // 27 offsets -> 14 pairs (last padded)
#define WFRAG_HALVES (4 * NPAIR * 64 * 8)   // 28672 f16 = 57344 B

// ---------------- ws layout ----------------
// featH : _Float16[NVOX*64]   offset 0           (51,200,000 B)
// wfrag : _Float16[28672]     offset 51,200,000  (57,344 B)
#define FEATH_OFF 0
#define WFRAG_OFF 51200000

typedef __attribute__((ext_vector_type(8))) _Float16 half8;
typedef __attribute__((ext_vector_type(4))) float float4v;

// feat fp32 -> fp16, 8 elements per thread
__global__ void cvt_feat_kernel(const float* __restrict__ f, _Float16* __restrict__ fh) {
    int t = blockIdx.x * blockDim.x + threadIdx.x;
    const int total = NVOX * CTOT / 8;   // 3,200,000
    if (t >= total) return;
    const float4* fp = (const float4*)f + (size_t)t * 2;
    float4 a = fp[0], b = fp[1];
    union { _Float16 h[8]; uint4 u; } r;
    r.h[0] = (_Float16)a.x; r.h[1] = (_Float16)a.y;
    r.h[2] = (_Float16)a.z; r.h[3] = (_Float16)a.w;
    r.h[4] = (_Float16)b.x; r.h[5] = (_Float16)b.y;
    r.h[6] = (_Float16)b.z; r.h[7] = (_Float16)b.w;
    ((uint4*)fh)[t] = r.u;
}

// weight[g][ko][ci][co] fp32 -> B-fragment layout f16:
// wfrag[g][p][lane][j] = w[g][2p + (quad>>1)][ci=(quad&1)*8+j][co=lane&15], quad=lane>>4
// (so that lane's 8 halves are B[ks=quad*8+j][n=lane&15] with ks = ko_sel*16 + ci)
__global__ void cvt_w_kernel(const float* __restrict__ w, _Float16* __restrict__ wf) {
    int t = blockIdx.x * blockDim.x + threadIdx.x;
    if (t >= WFRAG_HALVES) return;
    int j = t & 7;
    int l = (t >> 3) & 63;
    int gp = t >> 9;            // 0..55
    int p = gp % NPAIR;
    int g = gp / NPAIR;
    int co = l & 15;
    int quad = l >> 4;
    int ko = 2 * p + (quad >> 1);
    int ci = (quad & 1) * 8 + j;
    float val = (ko < KVOL) ? w[((g * KVOL + ko) * 16 + ci) * 16 + co] : 0.f;
    wf[t] = (_Float16)val;
}

__global__ __launch_bounds__(256) void conv_main_kernel(
        const _Float16* __restrict__ fh,
        const uint4*    __restrict__ wfrag,
        const float*    __restrict__ bias,
        const int*      __restrict__ nb,
        float* __restrict__ out) {
    __shared__ int s_nb[16 * 28];        // [v][k], k padded to 28 with -1
    const int tile = blockIdx.x;
    const int t = threadIdx.x;

    // coalesced nb stage: 432 contiguous dwords for this tile's 16 voxels
    const int* src = nb + (size_t)tile * (16 * KVOL);
    for (int j = t; j < 16 * KVOL; j += 256) {
        int v = j / KVOL;
        int k = j - v * KVOL;
        s_nb[v * 28 + k] = src[j];
    }
    if (t < 16) s_nb[t * 28 + 27] = -1;
    __syncthreads();

    const int lane = t & 63;
    const int g = t >> 6;                // wave index = group
    const int v = lane & 15;             // voxel within tile (A-frag row m)
    const int quad = lane >> 4;
    const int q2 = quad >> 1;            // which offset of the pair
    const int half = quad & 1;           // which 8-ci half

    // B-fragments resident in VGPRs (56 regs), loaded coalesced once
    uint4 wB[NPAIR];
#pragma unroll
    for (int p = 0; p < NPAIR; ++p)
        wB[p] = wfrag[(g * NPAIR + p) * 64 + lane];

    float4v acc = {0.f, 0.f, 0.f, 0.f};
    const _Float16* fbase = fh + g * 16 + half * 8;

#pragma unroll
    for (int p = 0; p < NPAIR; ++p) {
        int idx = s_nb[v * 28 + 2 * p + q2];
        bool m = idx >= 0;
        int idxc = m ? idx : 0;          // inactive lanes all hit row 0 (1 shared line)
        uint4 a = *(const uint4*)(fbase + (size_t)idxc * CTOT);
        a.x = m ? a.x : 0u;
        a.y = m ? a.y : 0u;
        a.z = m ? a.z : 0u;
        a.w = m ? a.w : 0u;
        half8 av = __builtin_bit_cast(half8, a);
        half8 bv = __builtin_bit_cast(half8, wB[p]);
        acc = __builtin_amdgcn_mfma_f32_16x16x32_f16(av, bv, acc, 0, 0, 0);
    }

    // C/D layout: col(co) = lane&15, row(voxel) = quad*4 + r
    const int co = lane & 15;
    const float breg = bias[g * 16 + co];
    float* ob = out + ((size_t)(tile * 16 + quad * 4)) * CTOT + g * 16 + co;
#pragma unroll
    for (int r = 0; r < 4; ++r)
        ob[(size_t)r * CTOT] = acc[r] + breg;
}

extern "C" void kernel_launch(void* const* d_in, const int* in_sizes, int n_in,
                              void* d_out, int out_size, void* d_ws, size_t ws_size,
                              hipStream_t stream) {
    const float* features = (const float*)d_in[0];
    const float* weight   = (const float*)d_in[1];
    const float* bias     = (const float*)d_in[2];
    const int*   nb       = (const int*)d_in[3];
    float* out = (float*)d_out;

    char* ws = (char*)d_ws;
    _Float16* featH = (_Float16*)(ws + FEATH_OFF);
    _Float16* wf    = (_Float16*)(ws + WFRAG_OFF);

    cvt_feat_kernel<<<(NVOX * CTOT / 8 + 255) / 256, 256, 0, stream>>>(features, featH);
    cvt_w_kernel<<<(WFRAG_HALVES + 255) / 256, 256, 0, stream>>>(weight, wf);
    conv_main_kernel<<<NTILES, 256, 0, stream>>>(featH, (const uint4*)wf, bias, nb, out);
}